// Round 4
// baseline (474.800 us; speedup 1.0000x reference)
//
#include <hip/hip_runtime.h>
#include <hip/hip_bf16.h>
#include <stdint.h>

#define HID    128
#define DT     0.1f
#define NITER  10
#define NTHR   1024         // 16 waves per block -> 4 waves/SIMD, 1 block/CU
#define NW     16
#define RPW    16           // rows per wave-chunk (wave-private)
#define NBLK   256          // 1 block per CU
#define NCH    4            // 256*16*16*4 = 262144 rows
#define SCALE  2.885390081777927f   // 2*log2(e) folded into W1..3/b1..3

typedef __attribute__((ext_vector_type(8))) short bf16x8;   // MFMA A/B frag
typedef __attribute__((ext_vector_type(4))) float f32x4;    // MFMA C/D frag
typedef __attribute__((ext_vector_type(2))) unsigned int u32x2;
typedef __attribute__((ext_vector_type(4))) unsigned int u32x4;

union FragU { bf16x8 v; uint32_t u[4]; };

// LDS: shared read-only weights (MFMA fragment order) + per-wave private
// activation buffers (no cross-wave traffic -> barrier-free main loop).
struct alignas(16) Smem {
    uint32_t w2f[8 * 4 * 64 * 4];   // 32 KB  [(ot*4+kt)*64+lane][4 u32]
    uint32_t w3f[8 * 4 * 64 * 4];   // 32 KB
    uint32_t w1f[8 * 64 * 4];       //  8 KB  [ot*64+lane][4 u32] (K=4 padded)
    float    b1[HID], b2[HID], b3[HID];   // 1.5 KB, pre-scaled
    uint16_t hbuf[NW * RPW * HID];  // 64 KB  per-wave swizzled [row][feat]
};  // 137.5 KB -> 1 block/CU, 16 waves = 4/SIMD

__device__ __forceinline__ uint16_t f2bf(float f) {
    uint32_t u = __float_as_uint(f);
    return (uint16_t)((u + 0x7fffu + ((u >> 16) & 1u)) >> 16);
}

__device__ __forceinline__ uint32_t pk2(float a, float b) {
    __hip_bfloat162 h = __float22bfloat162_rn(float2{a, b});
    return *reinterpret_cast<uint32_t*>(&h);
}

// 4x tanh with ONE v_rcp via batched (Montgomery) inversion.
// Inputs y = 2*log2(e)*x (scale pre-folded into W/b).
// tanh(x) = 1 - 2/(2^y + 1).  Clamp y<=30 so e<=2^30 and the 4-product
// <= 2^120 stays finite (rcp result >= 2^-120, normal).
__device__ __forceinline__ f32x4 tanh4(f32x4 y) {
    float e0 = __builtin_amdgcn_exp2f(fminf(y[0], 30.f)) + 1.0f;
    float e1 = __builtin_amdgcn_exp2f(fminf(y[1], 30.f)) + 1.0f;
    float e2 = __builtin_amdgcn_exp2f(fminf(y[2], 30.f)) + 1.0f;
    float e3 = __builtin_amdgcn_exp2f(fminf(y[3], 30.f)) + 1.0f;
    float p01   = e0 * e1;
    float p012  = p01 * e2;
    float p0123 = p012 * e3;
    float r     = __builtin_amdgcn_rcpf(p0123);
    float i3   = p012 * r;        // 1/e3
    float r012 = e3 * r;          // 1/(e0*e1*e2)
    float i2   = p01 * r012;      // 1/e2
    float r01  = e2 * r012;       // 1/(e0*e1)
    float i1   = e0 * r01;        // 1/e1
    float i0   = e1 * r01;        // 1/e0
    return (f32x4){fmaf(-2.f, i0, 1.f), fmaf(-2.f, i1, 1.f),
                   fmaf(-2.f, i2, 1.f), fmaf(-2.f, i3, 1.f)};
}

__device__ __forceinline__ float uread(const float* p) {
    return __uint_as_float(__builtin_amdgcn_readfirstlane(__float_as_uint(*p)));
}

// h-buffer: [row][feat] bf16, row stride 256 B, 16B-chunk XOR swizzle.
__device__ __forceinline__ void hstore(char* hb, int row, int ot, int g, const f32x4& a) {
    f32x4 tq = tanh4(a);
    int off = row * 256 + ((32 * ot + 8 * g) ^ ((row & 7) << 4));
    u32x2 p;
    p.x = pk2(tq[0], tq[1]);
    p.y = pk2(tq[2], tq[3]);
    *(u32x2*)(hb + off) = p;
}

__device__ __forceinline__ bf16x8 hload(const char* hb, int row, int kt, int g) {
    int off = row * 256 + ((64 * kt + 16 * g) ^ ((row & 7) << 4));
    return *(const bf16x8*)(hb + off);
}

// One dense layer for this wave's 16 rows: h <- tanh(h @ W + b), in place.
// All 4 input frags read before any store (per-wave in-order DS).
__device__ __forceinline__ void dense_layer(
    char* hb, const uint32_t* __restrict__ wf, const float* __restrict__ bias,
    int ln, int g, int lane)
{
    bf16x8 hf[4];
    #pragma unroll
    for (int kt = 0; kt < 4; ++kt)
        hf[kt] = hload(hb, ln, kt, g);
    #pragma unroll
    for (int ot = 0; ot < 8; ++ot) {
        f32x4 a = *(const f32x4*)&bias[ot * 16 + 4 * g];
        #pragma unroll
        for (int kt = 0; kt < 4; ++kt) {
            bf16x8 wfr = *(const bf16x8*)&wf[((ot * 4 + kt) * 64 + lane) * 4];
            a = __builtin_amdgcn_mfma_f32_16x16x32_bf16(wfr, hf[kt], a, 0, 0, 0);
        }
        hstore(hb, ln, ot, g, a);
    }
}

__global__ __launch_bounds__(NTHR, 4) void pinn_irk_rows(
    const float* __restrict__ x0g,
    const float* __restrict__ w1g, const float* __restrict__ b1g,
    const float* __restrict__ w2g, const float* __restrict__ b2g,
    const float* __restrict__ w3g, const float* __restrict__ b3g,
    const float* __restrict__ w4g, const float* __restrict__ b4g,
    const float* __restrict__ l1g, const float* __restrict__ l2g,
    const float* __restrict__ l3g, const float* __restrict__ l4g,
    const float* __restrict__ alg, const float* __restrict__ beg,
    float* __restrict__ outg)
{
    __shared__ Smem S;
    const int t    = threadIdx.x;
    const int blk  = blockIdx.x;
    const int lane = t & 63;
    const int w    = t >> 6;        // wave 0..15: owns its 16 rows end-to-end
    const int ln   = lane & 15;
    const int g    = lane >> 4;
    const bool owner = (g == 0);    // lane (ln,0) owns row base+ln

    // ---- uniform params -> SGPRs ----
    const float L0 = uread(l1g), L1v = uread(l2g), L2v = uread(l3g), L3v = uread(l4g);
    const float B40 = uread(b4g), B41 = uread(b4g + 1);
    const float B42 = uread(b4g + 2), B43 = uread(b4g + 3);
    const float BE0 = uread(beg), BE1 = uread(beg + 1);
    const float BE2 = uread(beg + 2), BE3 = uread(beg + 3);
    float A[16];
    #pragma unroll
    for (int i = 0; i < 16; ++i) A[i] = uread(alg + i);

    // ---- stage W2/W3 fragments (pre-scaled): elem j of frag (ot,kt,lane)
    //      = W[k=kt*32+8*(lane>>4)+j][m=ot*16+(lane&15)] ----
    for (int s = t; s < 2048; s += NTHR) {
        int lane_s = s & 63, kto = s >> 6;
        int kt = kto & 3, ot = kto >> 2;
        int m = ot * 16 + (lane_s & 15), gs = lane_s >> 4;
        uint32_t f2[4], f3[4];
        #pragma unroll
        for (int jj = 0; jj < 4; ++jj) {
            int k = kt * 32 + 8 * gs + 2 * jj;
            f2[jj] = (uint32_t)f2bf(w2g[k * HID + m] * SCALE)
                   | ((uint32_t)f2bf(w2g[(k + 1) * HID + m] * SCALE) << 16);
            f3[jj] = (uint32_t)f2bf(w3g[k * HID + m] * SCALE)
                   | ((uint32_t)f2bf(w3g[(k + 1) * HID + m] * SCALE) << 16);
        }
        *(u32x4*)&S.w2f[s * 4] = (u32x4){f2[0], f2[1], f2[2], f2[3]};
        *(u32x4*)&S.w3f[s * 4] = (u32x4){f3[0], f3[1], f3[2], f3[3]};
    }
    // ---- stage W1 fragments (K=4 real, rest zero) ----
    if (t < 512) {
        int lane_s = t & 63, ot = t >> 6;
        int gs = lane_s >> 4;
        uint32_t f[4] = {0u, 0u, 0u, 0u};
        if (gs == 0) {
            int m = ot * 16 + (lane_s & 15);
            f[0] = (uint32_t)f2bf(w1g[0 * HID + m] * SCALE)
                 | ((uint32_t)f2bf(w1g[1 * HID + m] * SCALE) << 16);
            f[1] = (uint32_t)f2bf(w1g[2 * HID + m] * SCALE)
                 | ((uint32_t)f2bf(w1g[3 * HID + m] * SCALE) << 16);
        }
        *(u32x4*)&S.w1f[t * 4] = (u32x4){f[0], f[1], f[2], f[3]};
    }
    if (t < HID) {
        S.b1[t] = b1g[t] * SCALE;
        S.b2[t] = b2g[t] * SCALE;
        S.b3[t] = b3g[t] * SCALE;
    }
    // ---- W4^T A-frags in registers (m=ln<4 real, else 0; unscaled) ----
    bf16x8 w4f[4];
    #pragma unroll
    for (int kt = 0; kt < 4; ++kt) {
        bf16x8 f;
        #pragma unroll
        for (int j = 0; j < 8; ++j) {
            int k = kt * 32 + 8 * g + j;
            f[j] = (ln < 4) ? (short)f2bf(w4g[k * 4 + ln]) : (short)0;
        }
        w4f[kt] = f;
    }
    __syncthreads();   // the ONLY block-wide barrier

    char* hb = (char*)&S.hbuf[w * RPW * HID];   // this wave's private 4 KB

    for (int ch = 0; ch < NCH; ++ch) {
        const int base = ((blk * NW + w) * NCH + ch) * RPW;
        // X0 of owner row (all lanes load; only g==0 values used)
        f32x4 XA0 = *(const f32x4*)&x0g[((base + ln) >> 2) * 4];
        f32x4 XA = XA0;
        f32x4 kvA = {0.f, 0.f, 0.f, 0.f};

        #pragma unroll 1
        for (int it = 0; it < NITER; ++it) {
            // ---- X -> B-frag (k=0..3 real, rest zero; zeros on g>0) ----
            FragU xa;
            xa.u[0] = owner ? pk2(XA[0], XA[1]) : 0u;
            xa.u[1] = owner ? pk2(XA[2], XA[3]) : 0u;
            xa.u[2] = 0u; xa.u[3] = 0u;

            // ---- L1: h = tanh(X @ W1 + b1) ----
            #pragma unroll
            for (int ot = 0; ot < 8; ++ot) {
                f32x4 bs = *(const f32x4*)&S.b1[ot * 16 + 4 * g];
                bf16x8 wfr = *(const bf16x8*)&S.w1f[(ot * 64 + lane) * 4];
                f32x4 a = __builtin_amdgcn_mfma_f32_16x16x32_bf16(wfr, xa.v, bs, 0, 0, 0);
                hstore(hb, ln, ot, g, a);
            }
            // ---- L2, L3 ----
            dense_layer(hb, S.w2f, S.b2, ln, g, lane);
            dense_layer(hb, S.w3f, S.b3, ln, g, lane);

            // ---- L4 + K + X update ----
            {
                bf16x8 hf[4];
                #pragma unroll
                for (int kt = 0; kt < 4; ++kt)
                    hf[kt] = hload(hb, ln, kt, g);
                f32x4 kA = {0.f, 0.f, 0.f, 0.f};
                #pragma unroll
                for (int kt = 0; kt < 4; ++kt)
                    kA = __builtin_amdgcn_mfma_f32_16x16x32_bf16(w4f[kt], hf[kt], kA, 0, 0, 0);
                // owner lanes (g==0) hold K[row][0..3] in kA regs
                float h0 = kA[0] + B40, h1 = kA[1] + B41;
                float h2 = kA[2] + B42, h3 = kA[3] + B43;
                kvA = (f32x4){-L0 * h2 - L1v * XA[2], -L0 * h3 - L1v * XA[3],
                               L2v * h0 + L3v * XA[0],  L2v * h1 + L3v * XA[1]};
                #pragma unroll
                for (int c = 0; c < 4; ++c) {
                    float s = kvA[0] * A[c] + kvA[1] * A[4 + c]
                            + kvA[2] * A[8 + c] + kvA[3] * A[12 + c];
                    XA[c] = fmaf(DT, s, XA0[c]);
                }
            }
        }

        // ---- final combine (wave-local via private LDS scratch) ----
        if (owner) {
            *(f32x4*)(hb + ln * 16) = kvA;
        }
        // per-wave in-order DS + compiler lgkmcnt make the reads safe
        if (lane < 16) {
            const float* kk = (const float*)hb;
            int bl_ = lane >> 2, i = lane & 3;
            float s = BE0 * kk[(bl_ * 4 + 0) * 4 + i]
                    + BE1 * kk[(bl_ * 4 + 1) * 4 + i]
                    + BE2 * kk[(bl_ * 4 + 2) * 4 + i]
                    + BE3 * kk[(bl_ * 4 + 3) * 4 + i];
            int idx = base + lane;   // = (base/4 + bl_)*4 + i
            outg[idx] = x0g[idx] + DT * s;
        }
    }
}

extern "C" void kernel_launch(void* const* d_in, const int* in_sizes, int n_in,
                              void* d_out, int out_size, void* d_ws, size_t ws_size,
                              hipStream_t stream) {
    (void)in_sizes; (void)n_in; (void)d_ws; (void)ws_size; (void)out_size;

    dim3 grid(NBLK);    // 1 block per CU, 16 waves each, barrier-free main loop
    dim3 block(NTHR);

    pinn_irk_rows<<<grid, block, 0, stream>>>(
        (const float*)d_in[0],
        (const float*)d_in[1],  (const float*)d_in[2],
        (const float*)d_in[3],  (const float*)d_in[4],
        (const float*)d_in[5],  (const float*)d_in[6],
        (const float*)d_in[7],  (const float*)d_in[8],
        (const float*)d_in[9],  (const float*)d_in[10],
        (const float*)d_in[11], (const float*)d_in[12],
        (const float*)d_in[13], (const float*)d_in[14],
        (float*)d_out);
}